// Round 3
// baseline (237.888 us; speedup 1.0000x reference)
//
#include <hip/hip_runtime.h>
#include <hip/hip_bf16.h>
#include <stdint.h>

// Conv2d 3x3 s1 p1: x (32,128,56,56) f32, w (256,128,3,3) f32, bias (256,), out (32,256,56,56) f32.
// bf16 MFMA implicit GEMM, K reordered kw-major: k' = kw*384 + ic*3 + kh.
// B[k'][q] = xp[plane(n,ic)][q + kh*64 + kw]; xp = padded bf16 x, rows 58, cols 64.
// Three pre-shifted copies of xp (shift 0/1/2 elements) make every B load 8B-aligned.

#define CB    32
#define CIC   128
#define CH    56
#define CW    56
#define COC   256
#define CK    1152
#define PLANES (CB*CIC)                 // 4096
#define PH    58
#define PW    64
#define PLANE_SZ (PH*PW)                // 3712
#define KB_STEPS (CK/64)                // 18
#define WT_SLAB (COC*64)                // 16384 elems per K-step slab
#define XS_ELEMS (PLANES*PLANE_SZ+512)  // 15,204,864 (tail pad, zero-filled)
#define XS_STRIDE XS_ELEMS              // copy stride in elements
#define NPLANE_D 475136                 // 128*3712 (one image's planes)
#define DEL_A 78016                     // 21*3712 + 64  (i3 += 64, no kh wrap)
#define DEL_B 3520                      // extra when kh wraps (2->0, ic+1)

typedef short     bf16x8  __attribute__((ext_vector_type(8)));
typedef float     f32x4   __attribute__((ext_vector_type(4)));
typedef unsigned short u16x8 __attribute__((ext_vector_type(8)));

// ---------------- pad + bf16 cast: x -> xs copy0 [4096][58][64] + zero tail ----------------
__global__ __launch_bounds__(256)
void pad_x_kernel(const float* __restrict__ x, ushort* __restrict__ xp, int total4) {
    int t = blockIdx.x * 256 + threadIdx.x;
    if (t >= total4) return;
    int i4 = t * 4;
    int plane = i4 / PLANE_SZ;
    int rem   = i4 - plane * PLANE_SZ;
    int r = rem >> 6;
    int c0 = rem & 63;
    ushort4 v;
    ushort* pv = (ushort*)&v;
#pragma unroll
    for (int j = 0; j < 4; ++j) {
        int c = c0 + j;
        float val = 0.f;
        if (plane < PLANES && r >= 1 && r <= CH && c >= 1 && c <= CW) {
            val = x[((size_t)plane * CH + (r - 1)) * CW + (c - 1)];
        }
        __hip_bfloat16 b = __float2bfloat16(val);
        pv[j] = *(ushort*)&b;
    }
    *(ushort4*)(xp + i4) = v;
}

// ---------------- build shifted copies: xs1[i] = xs0[i+1], xs2[i] = xs0[i+2] ----------------
__global__ __launch_bounds__(256)
void shift2_kernel(const ushort* __restrict__ xs0, ushort* __restrict__ xs1,
                   ushort* __restrict__ xs2, int total8) {
    int t = blockIdx.x * 256 + threadIdx.x;
    if (t >= total8) return;
    int i8 = t * 8;
    uint4 a = *(const uint4*)(xs0 + i8);
    uint32_t b = *(const uint32_t*)(xs0 + i8 + 8);   // may touch 4B past region: benign (dead tail)
    uint4 c1, c2;
    c1.x = (uint32_t)((((uint64_t)a.y << 32) | a.x) >> 16);
    c1.y = (uint32_t)((((uint64_t)a.z << 32) | a.y) >> 16);
    c1.z = (uint32_t)((((uint64_t)a.w << 32) | a.z) >> 16);
    c1.w = (uint32_t)((((uint64_t)b   << 32) | a.w) >> 16);
    c2.x = a.y; c2.y = a.z; c2.z = a.w; c2.w = b;
    *(uint4*)(xs1 + i8) = c1;
    *(uint4*)(xs2 + i8) = c2;
}

// ---------------- weight repack: OIHW f32 -> Wt[kb][oc][64] bf16, kw-major K, baked swizzle ----------------
__global__ __launch_bounds__(256)
void repack_wt_kernel(const float* __restrict__ w, ushort* __restrict__ wt) {
    int t = blockIdx.x * 256 + threadIdx.x;
    if (t >= COC * CK) return;
    int oc = t / CK;
    int k2 = t - oc * CK;                 // dest k' (kw-major)
    int kw  = k2 / 384;
    int rem = k2 - kw * 384;
    int ic  = rem / 3;
    int kh  = rem - ic * 3;
    int korig = ic * 9 + kh * 3 + kw;
    int kb = k2 >> 6, kl = k2 & 63;
    // 16B-chunk XOR swizzle: chunk kl>>3 stored at slot (kl>>3)^(oc&7)
    int pos = kb * WT_SLAB + (oc << 6) + (kl ^ ((oc & 7) << 3));
    __hip_bfloat16 b = __float2bfloat16(w[(size_t)oc * CK + korig]);
    wt[pos] = *(ushort*)&b;
}

// ---------------- async global->LDS helper ----------------
__device__ __forceinline__ void gload_lds16(const void* g, void* l) {
    __builtin_amdgcn_global_load_lds(
        (const __attribute__((address_space(1))) uint32_t*)g,
        (__attribute__((address_space(3))) uint32_t*)l, 16, 0, 0);
}

// ---------------- MFMA implicit-GEMM conv ----------------
// grid (896, 2): bx -> (n = bx/28, q0 = (bx%28)*128), by -> oc0 = by*128.
// block 256 = 4 waves, wave tile 64(oc) x 64(q), frags 4x4 of 16x16x32.
// MODE 0: 3 pre-shifted copies (aligned uint2 loads). MODE 1: single copy + funnel shift.
template <int MODE>
__global__ __launch_bounds__(256, 2)
void conv_mfma_kernel(const ushort* __restrict__ wt, const ushort* __restrict__ xs,
                      const float* __restrict__ bias, float* __restrict__ out) {
    __shared__ ushort ldsA[128 * 64];   // [oc_l][k] chunks swizzled: slot = chunk ^ (oc_l&7)
    __shared__ ushort ldsB[128 * 64];   // [q_l][k]  chunks swizzled: slot = chunk ^ (q_l&7)

    const int tid  = threadIdx.x;
    const int lane = tid & 63;
    const int wid  = tid >> 6;
    const int wm   = wid >> 1, wn = wid & 1;
    const int n_img = blockIdx.x / 28;
    const int q0    = (blockIdx.x % 28) * 128;
    const int oc0   = blockIdx.y * 128;

    const int ko = tid & 7;        // k-octet owned for B staging
    const int qq = tid >> 3;       // q-quad index 0..31 (q_local = 4*qq + i)

    f32x4 acc[4][4];
#pragma unroll
    for (int m = 0; m < 4; ++m)
#pragma unroll
        for (int n = 0; n < 4; ++n)
#pragma unroll
            for (int e = 0; e < 4; ++e) acc[m][n][e] = 0.f;

    // ---- per-thread B address state (incremental k' = kb*64 + ko*8 + r walk) ----
    int off[8], khs[8];
    int i3 = ko * 8;               // i3 for r=0; all r share the same kb-crossing behavior
    {
        const int nbase = n_img * NPLANE_D + q0 + 4 * qq;
#pragma unroll
        for (int r = 0; r < 8; ++r) {
            int kp = ko * 8 + r;            // k' at kb=0 (< 64 -> kw = 0)
            int ic = kp / 3;
            int kh = kp - ic * 3;
            off[r] = nbase + ic * PLANE_SZ + kh * PW;
            khs[r] = kh;
        }
    }

    // ---- precomputed LDS addresses (loop-invariant) ----
    uint32_t wbyte[4];
#pragma unroll
    for (int i = 0; i < 4; ++i) {
        int q = 4 * qq + i;
        wbyte[i] = (uint32_t)(q * 128 + ((ko ^ (q & 7)) << 4));
    }
    uint32_t fr_off[2];            // frag-read swizzled chunk offset, kk = 0,1 (same for A and B)
#pragma unroll
    for (int kk = 0; kk < 2; ++kk) {
        int octet = kk * 4 + (lane >> 4);
        fr_off[kk] = (uint32_t)((octet ^ (lane & 7)) << 4);
    }
    const uint32_t abase = (uint32_t)((wm * 64 + (lane & 15)) * 128);
    const uint32_t bbase = (uint32_t)((wn * 64 + (lane & 15)) * 128);

    for (int kb = 0; kb < KB_STEPS; ++kb) {
        // ---- B global loads (issue early, overlap with prev MFMA) ----
        uint2 bqd[8];
        if (MODE == 0) {
#pragma unroll
            for (int r = 0; r < 8; ++r)
                bqd[r] = *(const uint2*)(xs + off[r]);
        } else {
#pragma unroll
            for (int r = 0; r < 8; ++r) {
                int a0 = off[r] & ~3;
                int s  = off[r] & 3;            // == kw
                uint2 d01 = *(const uint2*)(xs + a0);
                uint32_t d2 = *(const uint32_t*)(xs + a0 + 4);
                bqd[r].x = (uint32_t)(((((uint64_t)d01.y) << 32) | d01.x) >> (16 * s));
                bqd[r].y = (uint32_t)(((((uint64_t)d2)    << 32) | d01.y) >> (16 * s));
            }
        }

        // ---- advance state to kb+1 ----
        const bool cross = (i3 + 64 >= 384);   // kw boundary (uniform across r and lanes' r-offsets)
        i3 = cross ? (i3 + 64 - 384) : (i3 + 64);
#pragma unroll
        for (int r = 0; r < 8; ++r) {
            bool khw = (khs[r] == 2);
            khs[r] = khw ? 0 : (khs[r] + 1);
            off[r] += DEL_A + (khw ? DEL_B : 0);
            if (cross) off[r] += (MODE == 0 ? (XS_STRIDE - NPLANE_D) : (1 - NPLANE_D));
        }

        __syncthreads();   // previous iteration's frag reads done

        // ---- A stage: global_load_lds, 16 KB linear (swizzle pre-baked in Wt) ----
        {
            const char* src = (const char*)(wt + (size_t)kb * WT_SLAB + oc0 * 64);
            char* dstbase = (char*)ldsA;
#pragma unroll
            for (int c = 0; c < 4; ++c) {
                int chunk = (wid * 4 + c) * 1024;
                gload_lds16(src + chunk + lane * 16, dstbase + chunk);
            }
        }

        // ---- B stage: register repack -> 4x ds_write_b128, 2-way max ----
#pragma unroll
        for (int i = 0; i < 4; ++i) {
            u16x8 vv;
#pragma unroll
            for (int r = 0; r < 8; ++r) {
                uint32_t w32 = (i < 2) ? bqd[r].x : bqd[r].y;
                vv[r] = (unsigned short)(w32 >> (16 * (i & 1)));
            }
            *(u16x8*)((char*)ldsB + wbyte[i]) = vv;
        }

        __syncthreads();   // implies vmcnt(0) lgkmcnt(0): gload_lds + ds_write drained

        // ---- MFMA: 2 k-halves x 16 mfma ----
#pragma unroll
        for (int kk = 0; kk < 2; ++kk) {
            bf16x8 af[4], bfr[4];
#pragma unroll
            for (int m = 0; m < 4; ++m)
                af[m] = *(const bf16x8*)((const char*)ldsA + (abase + m * 2048 + fr_off[kk]));
#pragma unroll
            for (int n = 0; n < 4; ++n)
                bfr[n] = *(const bf16x8*)((const char*)ldsB + (bbase + n * 2048 + fr_off[kk]));
#pragma unroll
            for (int m = 0; m < 4; ++m)
#pragma unroll
                for (int n = 0; n < 4; ++n)
                    acc[m][n] = __builtin_amdgcn_mfma_f32_16x16x32_bf16(af[m], bfr[n], acc[m][n], 0, 0, 0);
        }
    }

    // ---- epilogue: bias + store (discard w >= 56) ----
#pragma unroll
    for (int m = 0; m < 4; ++m) {
        float bv[4];
        int oc_b = oc0 + wm * 64 + m * 16 + (lane >> 4) * 4;
#pragma unroll
        for (int r = 0; r < 4; ++r) bv[r] = bias[oc_b + r];
#pragma unroll
        for (int n = 0; n < 4; ++n) {
            int q_virt = q0 + wn * 64 + n * 16 + (lane & 15);
            int wcol = q_virt & 63;
            if (wcol >= CW) continue;
            int h = q_virt >> 6;
#pragma unroll
            for (int r = 0; r < 4; ++r) {
                int oc = oc_b + r;
                out[(((size_t)n_img * COC + oc) * CH + h) * CW + wcol] = acc[m][n][r] + bv[r];
            }
        }
    }
}

// ---------------- fp32 direct fallback (no workspace needed) ----------------
__global__ __launch_bounds__(256)
void conv3x3_fallback(const float* __restrict__ x, const float* __restrict__ w,
                      const float* __restrict__ bias, float* __restrict__ out) {
    const int ow  = threadIdx.x & 63;
    const int ocg = threadIdx.x >> 6;
    const int oh  = blockIdx.y;
    const int n   = blockIdx.z;
    if (ow >= CW) return;
    const int oc0 = blockIdx.x * 32 + ocg * 8;
    float acc[8];
#pragma unroll
    for (int j = 0; j < 8; ++j) acc[j] = 0.f;
    const float* xn = x + (size_t)n * CIC * CH * CW;
    for (int ic = 0; ic < CIC; ++ic) {
        const float* xc = xn + (size_t)ic * CH * CW;
#pragma unroll
        for (int kh = 0; kh < 3; ++kh) {
            const int ih = oh + kh - 1;
            if ((unsigned)ih >= (unsigned)CH) continue;
            const float* xr = xc + ih * CW;
            const float xm = (ow > 0)      ? xr[ow - 1] : 0.f;
            const float x0 =                 xr[ow];
            const float xp_ = (ow < CW - 1) ? xr[ow + 1] : 0.f;
#pragma unroll
            for (int j = 0; j < 8; ++j) {
                const float* wj = w + (size_t)(oc0 + j) * CK + ic * 9 + kh * 3;
                acc[j] = fmaf(wj[0], xm, acc[j]);
                acc[j] = fmaf(wj[1], x0, acc[j]);
                acc[j] = fmaf(wj[2], xp_, acc[j]);
            }
        }
    }
    const size_t obase = (((size_t)n * COC + oc0) * CH + oh) * CW + ow;
#pragma unroll
    for (int j = 0; j < 8; ++j)
        out[obase + (size_t)j * CH * CW] = acc[j] + bias[oc0 + j];
}

extern "C" void kernel_launch(void* const* d_in, const int* in_sizes, int n_in,
                              void* d_out, int out_size, void* d_ws, size_t ws_size,
                              hipStream_t stream) {
    const float* x    = (const float*)d_in[0];
    const float* w    = (const float*)d_in[1];
    const float* bias = (const float*)d_in[2];
    float* out        = (float*)d_out;

    const size_t xs_off   = 1u << 20;                                   // wt below 1 MB
    const size_t xs_bytes = (size_t)XS_ELEMS * sizeof(ushort);          // 30,409,728
    const size_t need1    = xs_off + xs_bytes;                          // ~31.5 MB
    const size_t need3    = xs_off + 3 * xs_bytes;                      // ~92.3 MB

    if (ws_size < need1) {
        dim3 grid(COC / 32, CH, CB);
        conv3x3_fallback<<<grid, 256, 0, stream>>>(x, w, bias, out);
        return;
    }

    ushort* wt  = (ushort*)d_ws;
    ushort* xs0 = (ushort*)((char*)d_ws + xs_off);

    const int total4 = XS_ELEMS / 4;
    pad_x_kernel<<<(total4 + 255) / 256, 256, 0, stream>>>(x, xs0, total4);
    repack_wt_kernel<<<(COC * CK + 255) / 256, 256, 0, stream>>>(w, wt);

    dim3 grid(28 * CB, 2);
    if (ws_size >= need3) {
        ushort* xs1 = xs0 + XS_STRIDE;
        ushort* xs2 = xs1 + XS_STRIDE;
        const int total8 = XS_ELEMS / 8;
        shift2_kernel<<<(total8 + 255) / 256, 256, 0, stream>>>(xs0, xs1, xs2, total8);
        conv_mfma_kernel<0><<<grid, 256, 0, stream>>>(wt, xs0, bias, out);
    } else {
        conv_mfma_kernel<1><<<grid, 256, 0, stream>>>(wt, xs0, bias, out);
    }
}

// Round 4
// 209.073 us; speedup vs baseline: 1.1378x; 1.1378x over previous
//
#include <hip/hip_runtime.h>
#include <hip/hip_bf16.h>
#include <stdint.h>

// Conv2d 3x3 s1 p1: x (32,128,56,56) f32, w (256,128,3,3) f32, bias (256,), out (32,256,56,56) f32.
// bf16 MFMA implicit GEMM, K reordered kw-major: k' = kw*384 + ic*3 + kh.
// B[k'][q] = xs[plane(n,ic)][q + kh*64 + kw]; xs = padded bf16 x, rows 58, cols 64 (single copy).
// Round 4: double-buffered LDS + T14 pipeline (issue loads -> MFMA -> write LDS -> 1 barrier/kb).

#define CB    32
#define CIC   128
#define CH    56
#define CW    56
#define COC   256
#define CK    1152
#define PLANES (CB*CIC)                 // 4096
#define PH    58
#define PW    64
#define PLANE_SZ (PH*PW)                // 3712
#define KB_STEPS (CK/64)                // 18
#define WT_SLAB (COC*64)                // 16384 elems per K-step slab
#define XS_ELEMS (PLANES*PLANE_SZ+512)  // tail pad, zero-filled
#define NPLANE_D 475136                 // 128*3712 (one image's planes)
#define DEL_A 78016                     // 21*3712 + 64  (k' += 64, no kh wrap)
#define DEL_B 3520                      // extra when kh wraps (2->0, ic+1)

typedef short     bf16x8  __attribute__((ext_vector_type(8)));
typedef float     f32x4   __attribute__((ext_vector_type(4)));
typedef unsigned short u16x8 __attribute__((ext_vector_type(8)));

// ---------------- pad + bf16 cast: x -> xs [4096][58][64] + zero tail ----------------
__global__ __launch_bounds__(256)
void pad_x_kernel(const float* __restrict__ x, ushort* __restrict__ xp, int total4) {
    int t = blockIdx.x * 256 + threadIdx.x;
    if (t >= total4) return;
    int i4 = t * 4;
    int plane = i4 / PLANE_SZ;
    int rem   = i4 - plane * PLANE_SZ;
    int r = rem >> 6;
    int c0 = rem & 63;
    ushort4 v;
    ushort* pv = (ushort*)&v;
#pragma unroll
    for (int j = 0; j < 4; ++j) {
        int c = c0 + j;
        float val = 0.f;
        if (plane < PLANES && r >= 1 && r <= CH && c >= 1 && c <= CW) {
            val = x[((size_t)plane * CH + (r - 1)) * CW + (c - 1)];
        }
        __hip_bfloat16 b = __float2bfloat16(val);
        pv[j] = *(ushort*)&b;
    }
    *(ushort4*)(xp + i4) = v;
}

// ---------------- weight repack: OIHW f32 -> Wt[kb][oc][64] bf16, kw-major K, baked swizzle ----------------
__global__ __launch_bounds__(256)
void repack_wt_kernel(const float* __restrict__ w, ushort* __restrict__ wt) {
    int t = blockIdx.x * 256 + threadIdx.x;
    if (t >= COC * CK) return;
    int oc = t / CK;
    int k2 = t - oc * CK;                 // dest k' (kw-major)
    int kw  = k2 / 384;
    int rem = k2 - kw * 384;
    int ic  = rem / 3;
    int kh  = rem - ic * 3;
    int korig = ic * 9 + kh * 3 + kw;
    int kb = k2 >> 6, kl = k2 & 63;
    // 16B-chunk XOR swizzle: chunk kl>>3 stored at slot (kl>>3)^(oc&7)
    int pos = kb * WT_SLAB + (oc << 6) + (kl ^ ((oc & 7) << 3));
    __hip_bfloat16 b = __float2bfloat16(w[(size_t)oc * CK + korig]);
    wt[pos] = *(ushort*)&b;
}

// ---------------- async global->LDS helper ----------------
__device__ __forceinline__ void gload_lds16(const void* g, void* l) {
    __builtin_amdgcn_global_load_lds(
        (const __attribute__((address_space(1))) uint32_t*)g,
        (__attribute__((address_space(3))) uint32_t*)l, 16, 0, 0);
}

// ---------------- MFMA implicit-GEMM conv, double-buffered pipeline ----------------
// grid (896, 2): bx -> (n = bx/28, q0 = (bx%28)*128), by -> oc0 = by*128.
// block 256 = 4 waves, wave tile 64(oc) x 64(q), frags 4x4 of 16x16x32.
// Per kb: issue A gload_lds(kb+1) + B reg loads(kb+1) -> MFMA(kb) -> write B(kb+1) -> barrier.
__global__ __launch_bounds__(256, 2)
void conv_mfma_pipe(const ushort* __restrict__ wt, const ushort* __restrict__ xs,
                    const float* __restrict__ bias, float* __restrict__ out) {
    __shared__ ushort ldsA[2 * 8192];   // [p][oc_l][k] chunks swizzled: slot = chunk ^ (oc_l&7)
    __shared__ ushort ldsB[2 * 8192];   // [p][q_l][k]  chunks swizzled: slot = chunk ^ (q_l&7)

    const int tid  = threadIdx.x;
    const int lane = tid & 63;
    const int wid  = tid >> 6;
    const int wm   = wid >> 1, wn = wid & 1;
    const int n_img = blockIdx.x / 28;
    const int q0    = (blockIdx.x % 28) * 128;
    const int oc0   = blockIdx.y * 128;

    const int ko = tid & 7;        // k-octet owned for B staging
    const int qq = tid >> 3;       // q-quad index 0..31 (q_local = 4*qq + i)

    f32x4 acc[4][4];
#pragma unroll
    for (int m = 0; m < 4; ++m)
#pragma unroll
        for (int n = 0; n < 4; ++n)
#pragma unroll
            for (int e = 0; e < 4; ++e) acc[m][n][e] = 0.f;

    // ---- per-thread B address state (incremental k' = kb*64 + ko*8 + r walk) ----
    int off[8], khs[8];
    int i3 = ko * 8;
    {
        const int nbase = n_img * NPLANE_D + q0 + 4 * qq;
#pragma unroll
        for (int r = 0; r < 8; ++r) {
            int kp = ko * 8 + r;            // k' at kb=0 (< 64 -> kw = 0)
            int ic = kp / 3;
            int kh = kp - ic * 3;
            off[r] = nbase + ic * PLANE_SZ + kh * PW;
            khs[r] = kh;
        }
    }

    // ---- precomputed LDS addresses (loop-invariant, buffer 0) ----
    uint32_t wbyte[4];
#pragma unroll
    for (int i = 0; i < 4; ++i) {
        int q = 4 * qq + i;
        wbyte[i] = (uint32_t)(q * 128 + ((ko ^ (q & 7)) << 4));
    }
    uint32_t fr_off[2];            // frag-read swizzled chunk offset (same for A and B)
#pragma unroll
    for (int kk = 0; kk < 2; ++kk) {
        int octet = kk * 4 + (lane >> 4);
        fr_off[kk] = (uint32_t)((octet ^ (lane & 7)) << 4);
    }
    const uint32_t abase = (uint32_t)((wm * 64 + (lane & 15)) * 128);
    const uint32_t bbase = (uint32_t)((wn * 64 + (lane & 15)) * 128);

    // ---- helpers ----
    auto loadB = [&](uint2* bq) {
#pragma unroll
        for (int r = 0; r < 8; ++r) {
            int a0 = off[r] & ~3;
            int s  = off[r] & 3;            // == kw, wave-uniform
            uint2 d01 = *(const uint2*)(xs + a0);
            uint32_t d2 = *(const uint32_t*)(xs + a0 + 4);
            bq[r].x = (uint32_t)(((((uint64_t)d01.y) << 32) | d01.x) >> (16 * s));
            bq[r].y = (uint32_t)(((((uint64_t)d2)    << 32) | d01.y) >> (16 * s));
        }
    };
    auto advance = [&]() {
        const bool cross = (i3 + 64 >= 384);   // kw boundary (uniform)
        i3 = cross ? (i3 + 64 - 384) : (i3 + 64);
#pragma unroll
        for (int r = 0; r < 8; ++r) {
            bool khw = (khs[r] == 2);
            khs[r] = khw ? 0 : (khs[r] + 1);
            off[r] += DEL_A + (khw ? DEL_B : 0);
            if (cross) off[r] += 1 - NPLANE_D;
        }
    };
    auto stageA = [&](int kbn, int pn) {
        const char* src = (const char*)(wt + (size_t)kbn * WT_SLAB + oc0 * 64);
        char* dst = (char*)ldsA + (pn << 14);
#pragma unroll
        for (int c = 0; c < 4; ++c) {
            int chunk = (wid * 4 + c) * 1024;
            gload_lds16(src + chunk + lane * 16, dst + chunk);
        }
    };
    auto writeB = [&](const uint2* bq, int pn) {
        char* base = (char*)ldsB + (pn << 14);
#pragma unroll
        for (int i = 0; i < 4; ++i) {
            u16x8 vv;
#pragma unroll
            for (int r = 0; r < 8; ++r) {
                uint32_t w32 = (i < 2) ? bq[r].x : bq[r].y;
                vv[r] = (unsigned short)(w32 >> (16 * (i & 1)));
            }
            *(u16x8*)(base + wbyte[i]) = vv;
        }
    };

    // ---- prologue: fill buffer 0 for kb=0 ----
    uint2 bq[8];
    stageA(0, 0);
    loadB(bq);
    advance();
    writeB(bq, 0);       // compiler inserts vmcnt wait on bq here
    __syncthreads();     // drains gload_lds(A0) too

    // ---- main loop: one barrier per kb ----
    for (int kb = 0; kb < KB_STEPS; ++kb) {
        const int p = kb & 1;
        const bool more = (kb < KB_STEPS - 1);
        if (more) {
            stageA(kb + 1, p ^ 1);     // async global->LDS, other buffer
            loadB(bq);                 // B(kb+1) into regs, no wait yet
            advance();
        }
        // MFMA on buffer p (latency of the loads above hides under this)
        const uint32_t ps = (uint32_t)(p << 14);
#pragma unroll
        for (int kk = 0; kk < 2; ++kk) {
            bf16x8 af[4], bfr[4];
#pragma unroll
            for (int m = 0; m < 4; ++m)
                af[m] = *(const bf16x8*)((const char*)ldsA + (ps + abase + m * 2048 + fr_off[kk]));
#pragma unroll
            for (int n = 0; n < 4; ++n)
                bfr[n] = *(const bf16x8*)((const char*)ldsB + (ps + bbase + n * 2048 + fr_off[kk]));
#pragma unroll
            for (int m = 0; m < 4; ++m)
#pragma unroll
                for (int n = 0; n < 4; ++n)
                    acc[m][n] = __builtin_amdgcn_mfma_f32_16x16x32_bf16(af[m], bfr[n], acc[m][n], 0, 0, 0);
        }
        if (more) writeB(bq, p ^ 1);   // vmcnt wait lands here, after the MFMAs
        __syncthreads();
    }

    // ---- epilogue: bias + store (discard w >= 56) ----
#pragma unroll
    for (int m = 0; m < 4; ++m) {
        float bv[4];
        int oc_b = oc0 + wm * 64 + m * 16 + (lane >> 4) * 4;
#pragma unroll
        for (int r = 0; r < 4; ++r) bv[r] = bias[oc_b + r];
#pragma unroll
        for (int n = 0; n < 4; ++n) {
            int q_virt = q0 + wn * 64 + n * 16 + (lane & 15);
            int wcol = q_virt & 63;
            if (wcol >= CW) continue;
            int h = q_virt >> 6;
#pragma unroll
            for (int r = 0; r < 4; ++r) {
                int oc = oc_b + r;
                out[(((size_t)n_img * COC + oc) * CH + h) * CW + wcol] = acc[m][n][r] + bv[r];
            }
        }
    }
}

// ---------------- fp32 direct fallback (no workspace needed) ----------------
__global__ __launch_bounds__(256)
void conv3x3_fallback(const float* __restrict__ x, const float* __restrict__ w,
                      const float* __restrict__ bias, float* __restrict__ out) {
    const int ow  = threadIdx.x & 63;
    const int ocg = threadIdx.x >> 6;
    const int oh  = blockIdx.y;
    const int n   = blockIdx.z;
    if (ow >= CW) return;
    const int oc0 = blockIdx.x * 32 + ocg * 8;
    float acc[8];
#pragma unroll
    for (int j = 0; j < 8; ++j) acc[j] = 0.f;
    const float* xn = x + (size_t)n * CIC * CH * CW;
    for (int ic = 0; ic < CIC; ++ic) {
        const float* xc = xn + (size_t)ic * CH * CW;
#pragma unroll
        for (int kh = 0; kh < 3; ++kh) {
            const int ih = oh + kh - 1;
            if ((unsigned)ih >= (unsigned)CH) continue;
            const float* xr = xc + ih * CW;
            const float xm = (ow > 0)      ? xr[ow - 1] : 0.f;
            const float x0 =                 xr[ow];
            const float xp_ = (ow < CW - 1) ? xr[ow + 1] : 0.f;
#pragma unroll
            for (int j = 0; j < 8; ++j) {
                const float* wj = w + (size_t)(oc0 + j) * CK + ic * 9 + kh * 3;
                acc[j] = fmaf(wj[0], xm, acc[j]);
                acc[j] = fmaf(wj[1], x0, acc[j]);
                acc[j] = fmaf(wj[2], xp_, acc[j]);
            }
        }
    }
    const size_t obase = (((size_t)n * COC + oc0) * CH + oh) * CW + ow;
#pragma unroll
    for (int j = 0; j < 8; ++j)
        out[obase + (size_t)j * CH * CW] = acc[j] + bias[oc0 + j];
}

extern "C" void kernel_launch(void* const* d_in, const int* in_sizes, int n_in,
                              void* d_out, int out_size, void* d_ws, size_t ws_size,
                              hipStream_t stream) {
    const float* x    = (const float*)d_in[0];
    const float* w    = (const float*)d_in[1];
    const float* bias = (const float*)d_in[2];
    float* out        = (float*)d_out;

    const size_t xs_off   = 1u << 20;                                   // wt below 1 MB
    const size_t xs_bytes = (size_t)XS_ELEMS * sizeof(ushort);          // ~30.4 MB
    const size_t need     = xs_off + xs_bytes;                          // ~31.4 MB

    if (ws_size < need) {
        dim3 grid(COC / 32, CH, CB);
        conv3x3_fallback<<<grid, 256, 0, stream>>>(x, w, bias, out);
        return;
    }

    ushort* wt  = (ushort*)d_ws;
    ushort* xs0 = (ushort*)((char*)d_ws + xs_off);

    const int total4 = XS_ELEMS / 4;
    pad_x_kernel<<<(total4 + 255) / 256, 256, 0, stream>>>(x, xs0, total4);
    repack_wt_kernel<<<(COC * CK + 255) / 256, 256, 0, stream>>>(w, wt);

    dim3 grid(28 * CB, 2);
    conv_mfma_pipe<<<grid, 256, 0, stream>>>(wt, xs0, bias, out);
}

// Round 5
// 202.383 us; speedup vs baseline: 1.1754x; 1.0331x over previous
//
#include <hip/hip_runtime.h>
#include <hip/hip_bf16.h>
#include <stdint.h>

// Conv2d 3x3 s1 p1: x (32,128,56,56) f32, w (256,128,3,3) f32, bias (256,), out (32,256,56,56) f32.
// bf16 MFMA implicit GEMM, ic-major K (k = ic*9 + kh*3 + kw) for L2 locality.
// B[k][q] = xs[plane(n,ic)][q + kh*64 + kw]; xs = padded bf16 x, rows 58, cols 64.
// Round 5: ic-major locality + incremental addressing + XCD image-grouped remap + dbuf pipeline.

#define CB    32
#define CIC   128
#define CH    56
#define CW    56
#define COC   256
#define CK    1152
#define PLANES (CB*CIC)                 // 4096
#define PH    58
#define PW    64
#define PLANE_SZ (PH*PW)                // 3712
#define KB_STEPS (CK/64)                // 18
#define WT_SLAB (COC*64)                // 16384 elems per K-step slab
#define XS_ELEMS (PLANES*PLANE_SZ+512)  // tail pad, zero-filled
#define NPLANE_D 475136                 // 128*3712 (one image's planes)

typedef short     bf16x8  __attribute__((ext_vector_type(8)));
typedef float     f32x4   __attribute__((ext_vector_type(4)));
typedef unsigned short u16x8 __attribute__((ext_vector_type(8)));

// ---------------- pad + bf16 cast: x -> xs [4096][58][64] + zero tail ----------------
__global__ __launch_bounds__(256)
void pad_x_kernel(const float* __restrict__ x, ushort* __restrict__ xp, int total4) {
    int t = blockIdx.x * 256 + threadIdx.x;
    if (t >= total4) return;
    int i4 = t * 4;
    int plane = i4 / PLANE_SZ;
    int rem   = i4 - plane * PLANE_SZ;
    int r = rem >> 6;
    int c0 = rem & 63;
    ushort4 v;
    ushort* pv = (ushort*)&v;
#pragma unroll
    for (int j = 0; j < 4; ++j) {
        int c = c0 + j;
        float val = 0.f;
        if (plane < PLANES && r >= 1 && r <= CH && c >= 1 && c <= CW) {
            val = x[((size_t)plane * CH + (r - 1)) * CW + (c - 1)];
        }
        __hip_bfloat16 b = __float2bfloat16(val);
        pv[j] = *(ushort*)&b;
    }
    *(ushort4*)(xp + i4) = v;
}

// ---------------- weight repack: OIHW f32 -> Wt[kb][oc][64] bf16, ic-major K, baked swizzle ----------------
__global__ __launch_bounds__(256)
void repack_wt_kernel(const float* __restrict__ w, ushort* __restrict__ wt) {
    int t = blockIdx.x * 256 + threadIdx.x;
    if (t >= COC * CK) return;
    int oc = t / CK;
    int k  = t - oc * CK;                 // ic-major: source order == dest order
    int kb = k >> 6, kl = k & 63;
    // 16B-chunk XOR swizzle: chunk kl>>3 stored at slot (kl>>3)^(oc&7)
    int pos = kb * WT_SLAB + (oc << 6) + (kl ^ ((oc & 7) << 3));
    __hip_bfloat16 b = __float2bfloat16(w[t]);
    wt[pos] = *(ushort*)&b;
}

// ---------------- async global->LDS helper ----------------
__device__ __forceinline__ void gload_lds16(const void* g, void* l) {
    __builtin_amdgcn_global_load_lds(
        (const __attribute__((address_space(1))) uint32_t*)g,
        (__attribute__((address_space(3))) uint32_t*)l, 16, 0, 0);
}

// ---------------- MFMA implicit-GEMM conv, dbuf pipeline, XCD image grouping ----------------
// grid (1792): remapped so XCD d&7 owns images [4*(d&7), 4*(d&7)+4) (round-robin dispatch).
// block 256 = 4 waves, block tile 128(oc) x 128(q), wave 64x64, frags 4x4 of 16x16x32.
__global__ __launch_bounds__(256, 2)
void conv_mfma_pipe(const ushort* __restrict__ wt, const ushort* __restrict__ xs,
                    const float* __restrict__ bias, float* __restrict__ out) {
    __shared__ ushort ldsA[2 * 8192];   // [p][oc_l][k] chunks swizzled: slot = chunk ^ (oc_l&7)
    __shared__ ushort ldsB[2 * 8192];   // [p][q_l][k]  chunks swizzled: slot = chunk ^ (q_l&7)

    const int tid  = threadIdx.x;
    const int lane = tid & 63;
    const int wid  = tid >> 6;
    const int wm   = wid >> 1, wn = wid & 1;

    // ---- XCD-aware remap: image-mates share an XCD's L2 (bijection on [0,1792)) ----
    const int d    = blockIdx.x;
    const int xcd  = d & 7;
    const int slot = d >> 3;              // 0..223
    const int im4  = slot / 56;           // 0..3
    const int j    = slot - im4 * 56;     // 0..55
    const int n_img = 4 * xcd + im4;
    const int oc0   = (j / 28) * 128;
    const int q0    = (j - (j / 28) * 28) * 128;

    const int ko = tid & 7;        // k-octet owned for B staging
    const int qq = tid >> 3;       // q-quad index 0..31 (q_local = 4*qq + i)

    f32x4 acc[4][4];
#pragma unroll
    for (int m = 0; m < 4; ++m)
#pragma unroll
        for (int n = 0; n < 4; ++n)
#pragma unroll
            for (int e = 0; e < 4; ++e) acc[m][n][e] = 0.f;

    // ---- per-thread B address state: k = kb*64 + ko*8 + r, ic-major walk (+64 per kb) ----
    // off[r] = base + ic*PLANE_SZ + kh*64 + kw ; t9[r] = kh*3+kw tracks the phase.
    int off[8], t9[8], kw[8];
    {
        const int nbase = n_img * NPLANE_D + q0 + 4 * qq;
#pragma unroll
        for (int r = 0; r < 8; ++r) {
            int kp  = ko * 8 + r;           // < 64
            int ic  = kp / 9;
            int t   = kp - ic * 9;
            int kh  = t / 3;
            int kwv = t - kh * 3;
            off[r] = nbase + ic * PLANE_SZ + kh * PW + kwv;
            t9[r] = t;
            kw[r] = kwv;
        }
    }

    // ---- precomputed LDS addresses (loop-invariant) ----
    uint32_t wbyte[4];
#pragma unroll
    for (int i = 0; i < 4; ++i) {
        int q = 4 * qq + i;
        wbyte[i] = (uint32_t)(q * 128 + ((ko ^ (q & 7)) << 4));
    }
    uint32_t fr_off[2];            // frag-read swizzled chunk offset (same for A and B)
#pragma unroll
    for (int kk = 0; kk < 2; ++kk) {
        int octet = kk * 4 + (lane >> 4);
        fr_off[kk] = (uint32_t)((octet ^ (lane & 7)) << 4);
    }
    const uint32_t abase = (uint32_t)((wm * 64 + (lane & 15)) * 128);
    const uint32_t bbase = (uint32_t)((wn * 64 + (lane & 15)) * 128);

    // ---- helpers ----
    auto loadB = [&](uint2* bq) {
#pragma unroll
        for (int r = 0; r < 8; ++r) {
            int a0 = off[r] - kw[r];        // 8B-aligned (off & ~3; low bits == kw)
            uint2 d01 = *(const uint2*)(xs + a0);
            uint32_t d2 = *(const uint32_t*)(xs + a0 + 4);
            int s = kw[r];
            bq[r].x = (uint32_t)(((((uint64_t)d01.y) << 32) | d01.x) >> (16 * s));
            bq[r].y = (uint32_t)(((((uint64_t)d2)    << 32) | d01.y) >> (16 * s));
        }
    };
    auto advance = [&]() {                  // k += 64: ic += 7, t9 += 1 (mod 9, ic-carry)
#pragma unroll
        for (int r = 0; r < 8; ++r) {
            bool w9 = (t9[r] == 8);                    // kh 2->0, ic extra +1
            bool w3 = (kw[r] == 2) && !w9;             // kw 2->0, kh+1
            int dlt = w9 ? (PLANE_SZ - 130) : (w3 ? 62 : 1);  // -2*64-2+PLANE_SZ / +64-2 / +1
            off[r] += 7 * PLANE_SZ + dlt;
            t9[r] = w9 ? 0 : t9[r] + 1;
            kw[r] = (w9 | w3) ? 0 : kw[r] + 1;
        }
    };
    auto stageA = [&](int kbn, int pn) {
        const char* src = (const char*)(wt + (size_t)kbn * WT_SLAB + oc0 * 64);
        char* dst = (char*)ldsA + (pn << 14);
#pragma unroll
        for (int c = 0; c < 4; ++c) {
            int chunk = (wid * 4 + c) * 1024;
            gload_lds16(src + chunk + lane * 16, dst + chunk);
        }
    };
    auto writeB = [&](const uint2* bq, int pn) {
        char* base = (char*)ldsB + (pn << 14);
#pragma unroll
        for (int i = 0; i < 4; ++i) {
            u16x8 vv;
#pragma unroll
            for (int r = 0; r < 8; ++r) {
                uint32_t w32 = (i < 2) ? bq[r].x : bq[r].y;
                vv[r] = (unsigned short)(w32 >> (16 * (i & 1)));
            }
            *(u16x8*)(base + wbyte[i]) = vv;
        }
    };

    // ---- prologue: fill buffer 0 for kb=0 ----
    uint2 bq[8];
    loadB(bq);
    stageA(0, 0);
    advance();
    writeB(bq, 0);       // compiler inserts vmcnt wait on bq here
    __syncthreads();     // drains gload_lds(A0) too

    // ---- main loop: one barrier per kb ----
    for (int kb = 0; kb < KB_STEPS; ++kb) {
        const int p = kb & 1;
        const bool more = (kb < KB_STEPS - 1);
        if (more) {
            loadB(bq);                 // B(kb+1) into regs, no wait yet
            stageA(kb + 1, p ^ 1);     // async global->LDS, other buffer
            advance();
        }
        // MFMA on buffer p (latency of the loads above hides under this)
        const uint32_t ps = (uint32_t)(p << 14);
#pragma unroll
        for (int kk = 0; kk < 2; ++kk) {
            bf16x8 af[4], bfr[4];
#pragma unroll
            for (int m = 0; m < 4; ++m)
                af[m] = *(const bf16x8*)((const char*)ldsA + (ps + abase + m * 2048 + fr_off[kk]));
#pragma unroll
            for (int n = 0; n < 4; ++n)
                bfr[n] = *(const bf16x8*)((const char*)ldsB + (ps + bbase + n * 2048 + fr_off[kk]));
#pragma unroll
            for (int m = 0; m < 4; ++m)
#pragma unroll
                for (int n = 0; n < 4; ++n)
                    acc[m][n] = __builtin_amdgcn_mfma_f32_16x16x32_bf16(af[m], bfr[n], acc[m][n], 0, 0, 0);
        }
        if (more) writeB(bq, p ^ 1);   // vmcnt wait lands here, after the MFMAs
        __syncthreads();
    }

    // ---- epilogue: bias + store (discard w >= 56) ----
#pragma unroll
    for (int m = 0; m < 4; ++m) {
        float bv[4];
        int oc_b = oc0 + wm * 64 + m * 16 + (lane >> 4) * 4;
#pragma unroll
        for (int r = 0; r < 4; ++r) bv[r] = bias[oc_b + r];
#pragma unroll
        for (int n = 0; n < 4; ++n) {
            int q_virt = q0 + wn * 64 + n * 16 + (lane & 15);
            int wcol = q_virt & 63;
            if (wcol >= CW) continue;
            int h = q_virt >> 6;
#pragma unroll
            for (int r = 0; r < 4; ++r) {
                int oc = oc_b + r;
                out[(((size_t)n_img * COC + oc) * CH + h) * CW + wcol] = acc[m][n][r] + bv[r];
            }
        }
    }
}

// ---------------- fp32 direct fallback (no workspace needed) ----------------
__global__ __launch_bounds__(256)
void conv3x3_fallback(const float* __restrict__ x, const float* __restrict__ w,
                      const float* __restrict__ bias, float* __restrict__ out) {
    const int ow  = threadIdx.x & 63;
    const int ocg = threadIdx.x >> 6;
    const int oh  = blockIdx.y;
    const int n   = blockIdx.z;
    if (ow >= CW) return;
    const int oc0 = blockIdx.x * 32 + ocg * 8;
    float acc[8];
#pragma unroll
    for (int j = 0; j < 8; ++j) acc[j] = 0.f;
    const float* xn = x + (size_t)n * CIC * CH * CW;
    for (int ic = 0; ic < CIC; ++ic) {
        const float* xc = xn + (size_t)ic * CH * CW;
#pragma unroll
        for (int kh = 0; kh < 3; ++kh) {
            const int ih = oh + kh - 1;
            if ((unsigned)ih >= (unsigned)CH) continue;
            const float* xr = xc + ih * CW;
            const float xm = (ow > 0)      ? xr[ow - 1] : 0.f;
            const float x0 =                 xr[ow];
            const float xp_ = (ow < CW - 1) ? xr[ow + 1] : 0.f;
#pragma unroll
            for (int j = 0; j < 8; ++j) {
                const float* wj = w + (size_t)(oc0 + j) * CK + ic * 9 + kh * 3;
                acc[j] = fmaf(wj[0], xm, acc[j]);
                acc[j] = fmaf(wj[1], x0, acc[j]);
                acc[j] = fmaf(wj[2], xp_, acc[j]);
            }
        }
    }
    const size_t obase = (((size_t)n * COC + oc0) * CH + oh) * CW + ow;
#pragma unroll
    for (int j = 0; j < 8; ++j)
        out[obase + (size_t)j * CH * CW] = acc[j] + bias[oc0 + j];
}

extern "C" void kernel_launch(void* const* d_in, const int* in_sizes, int n_in,
                              void* d_out, int out_size, void* d_ws, size_t ws_size,
                              hipStream_t stream) {
    const float* x    = (const float*)d_in[0];
    const float* w    = (const float*)d_in[1];
    const float* bias = (const float*)d_in[2];
    float* out        = (float*)d_out;

    const size_t xs_off   = 1u << 20;                                   // wt below 1 MB
    const size_t xs_bytes = (size_t)XS_ELEMS * sizeof(ushort);          // ~30.4 MB
    const size_t need     = xs_off + xs_bytes;                          // ~31.4 MB

    if (ws_size < need) {
        dim3 grid(COC / 32, CH, CB);
        conv3x3_fallback<<<grid, 256, 0, stream>>>(x, w, bias, out);
        return;
    }

    ushort* wt  = (ushort*)d_ws;
    ushort* xs0 = (ushort*)((char*)d_ws + xs_off);

    const int total4 = XS_ELEMS / 4;
    pad_x_kernel<<<(total4 + 255) / 256, 256, 0, stream>>>(x, xs0, total4);
    repack_wt_kernel<<<(COC * CK + 255) / 256, 256, 0, stream>>>(w, wt);

    conv_mfma_pipe<<<dim3(1792), 256, 0, stream>>>(wt, xs0, bias, out);
}

// Round 6
// 184.142 us; speedup vs baseline: 1.2919x; 1.0991x over previous
//
#include <hip/hip_runtime.h>
#include <hip/hip_bf16.h>
#include <stdint.h>

// Conv2d 3x3 s1 p1: x (32,128,56,56) f32, w (256,128,3,3) f32, bias (256,), out (32,256,56,56) f32.
// bf16 MFMA implicit GEMM, ic-major K (k = ic*9 + kh*3 + kw).
// Round 6: counted-vmcnt deep pipeline (T3/T4): 3 A-buffers (gload_lds), 2 B-buffers,
// raw s_barrier + s_waitcnt vmcnt(4) -- loads stay in flight across barriers; no vmcnt(0) drain.

#define CB    32
#define CIC   128
#define CH    56
#define CW    56
#define COC   256
#define CK    1152
#define PLANES (CB*CIC)                 // 4096
#define PH    58
#define PW    64
#define PLANE_SZ (PH*PW)                // 3712
#define KB_STEPS (CK/64)                // 18
#define WT_SLAB (COC*64)                // 16384 elems per K-step slab
#define XS_ELEMS (PLANES*PLANE_SZ+512)  // tail pad, zero-filled
#define NPLANE_D 475136                 // 128*3712 (one image's planes)

#define FENCE asm volatile("" ::: "memory")
#define WAITVM4 asm volatile("s_waitcnt vmcnt(4)" ::: "memory")
#define WAITVM0 asm volatile("s_waitcnt vmcnt(0)" ::: "memory")
#define WAITLGKM0 asm volatile("s_waitcnt lgkmcnt(0)" ::: "memory")

typedef short     bf16x8  __attribute__((ext_vector_type(8)));
typedef float     f32x4   __attribute__((ext_vector_type(4)));
typedef unsigned short u16x8 __attribute__((ext_vector_type(8)));

// ---------------- pad + bf16 cast: x -> xs [4096][58][64] + zero tail ----------------
__global__ __launch_bounds__(256)
void pad_x_kernel(const float* __restrict__ x, ushort* __restrict__ xp, int total4) {
    int t = blockIdx.x * 256 + threadIdx.x;
    if (t >= total4) return;
    int i4 = t * 4;
    int plane = i4 / PLANE_SZ;
    int rem   = i4 - plane * PLANE_SZ;
    int r = rem >> 6;
    int c0 = rem & 63;
    ushort4 v;
    ushort* pv = (ushort*)&v;
#pragma unroll
    for (int j = 0; j < 4; ++j) {
        int c = c0 + j;
        float val = 0.f;
        if (plane < PLANES && r >= 1 && r <= CH && c >= 1 && c <= CW) {
            val = x[((size_t)plane * CH + (r - 1)) * CW + (c - 1)];
        }
        __hip_bfloat16 b = __float2bfloat16(val);
        pv[j] = *(ushort*)&b;
    }
    *(ushort4*)(xp + i4) = v;
}

// ---------------- weight repack: OIHW f32 -> Wt[kb][oc][64] bf16, ic-major K, baked swizzle ----------------
__global__ __launch_bounds__(256)
void repack_wt_kernel(const float* __restrict__ w, ushort* __restrict__ wt) {
    int t = blockIdx.x * 256 + threadIdx.x;
    if (t >= COC * CK) return;
    int oc = t / CK;
    int k  = t - oc * CK;                 // ic-major: source order == dest order
    int kb = k >> 6, kl = k & 63;
    // 16B-chunk XOR swizzle: chunk kl>>3 stored at slot (kl>>3)^(oc&7)
    int pos = kb * WT_SLAB + (oc << 6) + (kl ^ ((oc & 7) << 3));
    __hip_bfloat16 b = __float2bfloat16(w[t]);
    wt[pos] = *(ushort*)&b;
}

// ---------------- async global->LDS helper ----------------
__device__ __forceinline__ void gload_lds16(const void* g, void* l) {
    __builtin_amdgcn_global_load_lds(
        (const __attribute__((address_space(1))) uint32_t*)g,
        (__attribute__((address_space(3))) uint32_t*)l, 16, 0, 0);
}

// ---------------- MFMA implicit-GEMM conv, counted-vmcnt pipeline ----------------
// grid (1792): remapped so XCD d&7 owns images [4*(d&7), 4*(d&7)+4).
// block 256 = 4 waves, block tile 128(oc) x 128(q), wave 64x64, frags 4x4 of 16x16x32.
__global__ __launch_bounds__(256, 2)
void conv_mfma_pipe(const ushort* __restrict__ wt, const ushort* __restrict__ xs,
                    const float* __restrict__ bias, float* __restrict__ out) {
    __shared__ ushort ldsA[3 * 8192];   // 3 bufs: [oc_l][k] chunks swizzled slot = chunk ^ (oc_l&7)
    __shared__ ushort ldsB[2 * 8192];   // 2 bufs: [q_l][k]  chunks swizzled slot = chunk ^ (q_l&7)

    const int tid  = threadIdx.x;
    const int lane = tid & 63;
    const int wid  = tid >> 6;
    const int wm   = wid >> 1, wn = wid & 1;

    // ---- XCD-aware remap: image-mates share an XCD's L2 (bijection on [0,1792)) ----
    const int d    = blockIdx.x;
    const int xcd  = d & 7;
    const int slot = d >> 3;              // 0..223
    const int im4  = slot / 56;           // 0..3
    const int j    = slot - im4 * 56;     // 0..55
    const int n_img = 4 * xcd + im4;
    const int oc0   = (j / 28) * 128;
    const int q0    = (j - (j / 28) * 28) * 128;

    const int ko = tid & 7;        // k-octet owned for B staging
    const int qq = tid >> 3;       // q-quad index 0..31 (q_local = 4*qq + i)

    f32x4 acc[4][4];
#pragma unroll
    for (int m = 0; m < 4; ++m)
#pragma unroll
        for (int n = 0; n < 4; ++n)
#pragma unroll
            for (int e = 0; e < 4; ++e) acc[m][n][e] = 0.f;

    // ---- per-thread B address state: k = kb*64 + ko*8 + r, ic-major walk (+64 per kb) ----
    int off[8], t9[8], kw[8];
    {
        const int nbase = n_img * NPLANE_D + q0 + 4 * qq;
#pragma unroll
        for (int r = 0; r < 8; ++r) {
            int kp  = ko * 8 + r;           // < 64
            int ic  = kp / 9;
            int t   = kp - ic * 9;
            int kh  = t / 3;
            int kwv = t - kh * 3;
            off[r] = nbase + ic * PLANE_SZ + kh * PW + kwv;
            t9[r] = t;
            kw[r] = kwv;
        }
    }

    // ---- precomputed LDS addresses (loop-invariant) ----
    uint32_t wbyte[4];
#pragma unroll
    for (int i = 0; i < 4; ++i) {
        int q = 4 * qq + i;
        wbyte[i] = (uint32_t)(q * 128 + ((ko ^ (q & 7)) << 4));
    }
    uint32_t fr_off[2];            // frag-read swizzled chunk offset (same for A and B)
#pragma unroll
    for (int kk = 0; kk < 2; ++kk) {
        int octet = kk * 4 + (lane >> 4);
        fr_off[kk] = (uint32_t)((octet ^ (lane & 7)) << 4);
    }
    const uint32_t abase = (uint32_t)((wm * 64 + (lane & 15)) * 128);
    const uint32_t bbase = (uint32_t)((wn * 64 + (lane & 15)) * 128);

    // ---- helpers ----
    auto loadB = [&](uint2* bq) {
#pragma unroll
        for (int r = 0; r < 8; ++r) {
            int a0 = off[r] - kw[r];        // 8B-aligned
            uint2 d01 = *(const uint2*)(xs + a0);
            uint32_t d2 = *(const uint32_t*)(xs + a0 + 4);
            int s = kw[r];
            bq[r].x = (uint32_t)(((((uint64_t)d01.y) << 32) | d01.x) >> (16 * s));
            bq[r].y = (uint32_t)(((((uint64_t)d2)    << 32) | d01.y) >> (16 * s));
        }
    };
    auto advance = [&]() {                  // k += 64: ic += 7, t9 += 1 (mod 9, ic-carry)
#pragma unroll
        for (int r = 0; r < 8; ++r) {
            bool w9 = (t9[r] == 8);                    // kh 2->0, ic extra +1
            bool w3 = (kw[r] == 2) && !w9;             // kw 2->0, kh+1
            int dlt = w9 ? (PLANE_SZ - 130) : (w3 ? 62 : 1);
            off[r] += 7 * PLANE_SZ + dlt;
            t9[r] = w9 ? 0 : t9[r] + 1;
            kw[r] = (w9 | w3) ? 0 : kw[r] + 1;
        }
    };
    auto stageA = [&](int kbn, int bufn) {
        const char* src = (const char*)(wt + (size_t)kbn * WT_SLAB + oc0 * 64);
        char* dst = (char*)ldsA + (bufn << 14);
#pragma unroll
        for (int c = 0; c < 4; ++c) {
            int chunk = (wid * 4 + c) * 1024;
            gload_lds16(src + chunk + lane * 16, dst + chunk);
        }
    };
    auto writeB = [&](const uint2* bq, int bufn) {
        char* base = (char*)ldsB + (bufn << 14);
#pragma unroll
        for (int i = 0; i < 4; ++i) {
            u16x8 vv;
#pragma unroll
            for (int r = 0; r < 8; ++r) {
                uint32_t w32 = (i < 2) ? bq[r].x : bq[r].y;
                vv[r] = (unsigned short)(w32 >> (16 * (i & 1)));
            }
            *(u16x8*)(base + wbyte[i]) = vv;
        }
    };

    // ---- prologue: B(0) regs, A(0)->buf0, A(1)->buf1; counted wait; publish B(0) ----
    uint2 bq[8];
    loadB(bq);               // 16 vmem
    FENCE;
    stageA(0, 0);            // +4 gload_lds
    stageA(1, 1);            // +4 gload_lds
    advance();
    WAITVM4;                 // B(0) + A(0) done; A(1) may remain in flight
    writeB(bq, 0);
    WAITLGKM0;
    __builtin_amdgcn_s_barrier();

    // ---- main loop: counted vmcnt, loads alive across barriers ----
    for (int kb = 0; kb < KB_STEPS; ++kb) {
        const uint32_t psA = (uint32_t)((kb % 3) << 14);
        const uint32_t psB = (uint32_t)((kb & 1) << 14);
        const bool more  = (kb < KB_STEPS - 1);
        const bool more2 = (kb < KB_STEPS - 2);

        // kk=0 frag reads (issue first; VMEM issue below hides under their latency)
        bf16x8 af[4], bfr[4];
#pragma unroll
        for (int m = 0; m < 4; ++m)
            af[m] = *(const bf16x8*)((const char*)ldsA + (psA + abase + m * 2048 + fr_off[0]));
#pragma unroll
        for (int n = 0; n < 4; ++n)
            bfr[n] = *(const bf16x8*)((const char*)ldsB + (psB + bbase + n * 2048 + fr_off[0]));

        if (more) {
            loadB(bq);                         // 16 vmem for B(kb+1)
            FENCE;                             // pin issue order: B-loads before A-stage
            if (more2) stageA(kb + 2, (kb + 2) % 3);   // 4 gload_lds (stay in flight over barrier)
            advance();
        }

        __builtin_amdgcn_s_setprio(1);
#pragma unroll
        for (int m = 0; m < 4; ++m)
#pragma unroll
            for (int n = 0; n < 4; ++n)
                acc[m][n] = __builtin_amdgcn_mfma_f32_16x16x32_bf16(af[m], bfr[n], acc[m][n], 0, 0, 0);
        __builtin_amdgcn_s_setprio(0);

        // kk=1 frag reads + MFMA
        bf16x8 ag[4], bg[4];
#pragma unroll
        for (int m = 0; m < 4; ++m)
            ag[m] = *(const bf16x8*)((const char*)ldsA + (psA + abase + m * 2048 + fr_off[1]));
#pragma unroll
        for (int n = 0; n < 4; ++n)
            bg[n] = *(const bf16x8*)((const char*)ldsB + (psB + bbase + n * 2048 + fr_off[1]));

        __builtin_amdgcn_s_setprio(1);
#pragma unroll
        for (int m = 0; m < 4; ++m)
#pragma unroll
            for (int n = 0; n < 4; ++n)
                acc[m][n] = __builtin_amdgcn_mfma_f32_16x16x32_bf16(ag[m], bg[n], acc[m][n], 0, 0, 0);
        __builtin_amdgcn_s_setprio(0);

        if (more) {
            // steady state: newest 4 outstanding = A(kb+2) gloads; everything older
            // (B(kb+1) regs, A(kb+1) gloads) retired => safe to publish and cross.
            if (more2) { WAITVM4; } else { WAITVM0; }
            writeB(bq, (kb + 1) & 1);
            WAITLGKM0;                        // own ds_writes retired (cross-wave visibility)
            __builtin_amdgcn_s_barrier();     // NO vmcnt(0) here: A(kb+2) stays in flight
        }
    }

    // ---- epilogue: bias + store (discard w >= 56) ----
#pragma unroll
    for (int m = 0; m < 4; ++m) {
        float bv[4];
        int oc_b = oc0 + wm * 64 + m * 16 + (lane >> 4) * 4;
#pragma unroll
        for (int r = 0; r < 4; ++r) bv[r] = bias[oc_b + r];
#pragma unroll
        for (int n = 0; n < 4; ++n) {
            int q_virt = q0 + wn * 64 + n * 16 + (lane & 15);
            int wcol = q_virt & 63;
            if (wcol >= CW) continue;
            int h = q_virt >> 6;
#pragma unroll
            for (int r = 0; r < 4; ++r) {
                int oc = oc_b + r;
                out[(((size_t)n_img * COC + oc) * CH + h) * CW + wcol] = acc[m][n][r] + bv[r];
            }
        }
    }
}

// ---------------- fp32 direct fallback (no workspace needed) ----------------
__global__ __launch_bounds__(256)
void conv3x3_fallback(const float* __restrict__ x, const float* __restrict__ w,
                      const float* __restrict__ bias, float* __restrict__ out) {
    const int ow  = threadIdx.x & 63;
    const int ocg = threadIdx.x >> 6;
    const int oh  = blockIdx.y;
    const int n   = blockIdx.z;
    if (ow >= CW) return;
    const int oc0 = blockIdx.x * 32 + ocg * 8;
    float acc[8];
#pragma unroll
    for (int j = 0; j < 8; ++j) acc[j] = 0.f;
    const float* xn = x + (size_t)n * CIC * CH * CW;
    for (int ic = 0; ic < CIC; ++ic) {
        const float* xc = xn + (size_t)ic * CH * CW;
#pragma unroll
        for (int kh = 0; kh < 3; ++kh) {
            const int ih = oh + kh - 1;
            if ((unsigned)ih >= (unsigned)CH) continue;
            const float* xr = xc + ih * CW;
            const float xm = (ow > 0)      ? xr[ow - 1] : 0.f;
            const float x0 =                 xr[ow];
            const float xp_ = (ow < CW - 1) ? xr[ow + 1] : 0.f;
#pragma unroll
            for (int j = 0; j < 8; ++j) {
                const float* wj = w + (size_t)(oc0 + j) * CK + ic * 9 + kh * 3;
                acc[j] = fmaf(wj[0], xm, acc[j]);
                acc[j] = fmaf(wj[1], x0, acc[j]);
                acc[j] = fmaf(wj[2], xp_, acc[j]);
            }
        }
    }
    const size_t obase = (((size_t)n * COC + oc0) * CH + oh) * CW + ow;
#pragma unroll
    for (int j = 0; j < 8; ++j)
        out[obase + (size_t)j * CH * CW] = acc[j] + bias[oc0 + j];
}

extern "C" void kernel_launch(void* const* d_in, const int* in_sizes, int n_in,
                              void* d_out, int out_size, void* d_ws, size_t ws_size,
                              hipStream_t stream) {
    const float* x    = (const float*)d_in[0];
    const float* w    = (const float*)d_in[1];
    const float* bias = (const float*)d_in[2];
    float* out        = (float*)d_out;

    const size_t xs_off   = 1u << 20;                                   // wt below 1 MB
    const size_t xs_bytes = (size_t)XS_ELEMS * sizeof(ushort);          // ~30.4 MB
    const size_t need     = xs_off + xs_bytes;                          // ~31.4 MB

    if (ws_size < need) {
        dim3 grid(COC / 32, CH, CB);
        conv3x3_fallback<<<grid, 256, 0, stream>>>(x, w, bias, out);
        return;
    }

    ushort* wt  = (ushort*)d_ws;
    ushort* xs0 = (ushort*)((char*)d_ws + xs_off);

    const int total4 = XS_ELEMS / 4;
    pad_x_kernel<<<(total4 + 255) / 256, 256, 0, stream>>>(x, xs0, total4);
    repack_wt_kernel<<<(COC * CK + 255) / 256, 256, 0, stream>>>(w, wt);

    conv_mfma_pipe<<<dim3(1792), 256, 0, stream>>>(wt, xs0, bias, out);
}